// Round 8
// baseline (168.653 us; speedup 1.0000x reference)
//
#include <hip/hip_runtime.h>
#include <stdint.h>

typedef __attribute__((ext_vector_type(8))) short short8;
typedef __attribute__((ext_vector_type(4))) float f32x4;
typedef __attribute__((ext_vector_type(4))) unsigned short u16x4;
typedef __attribute__((ext_vector_type(8))) unsigned short u16x8;

#define DEV static __device__ __forceinline__

DEV unsigned short f2bf(float f) {
  unsigned u = __float_as_uint(f);
  u += 0x7FFFu + ((u >> 16) & 1u);
  return (unsigned short)(u >> 16);
}
DEV float bf2f(unsigned short s) { return __uint_as_float(((unsigned)s) << 16); }

// global -> LDS direct load, 16B per lane
DEV void gload16(const void* g, void* l) {
  __attribute__((address_space(1))) unsigned* gp =
      reinterpret_cast<__attribute__((address_space(1))) unsigned*>(
          reinterpret_cast<uintptr_t>(g));
  __attribute__((address_space(3))) unsigned* lp =
      reinterpret_cast<__attribute__((address_space(3))) unsigned*>(
          reinterpret_cast<uintptr_t>(l));
  __builtin_amdgcn_global_load_lds(gp, lp, 16, 0, 0);
}

// ---------------------------------------------------------------------------
// prep_w6: grid (256 couts, 6 sets). Thread t = cin; reads its 9 taps
// contiguously (36B), writes coalesced [tap][cin].
// ---------------------------------------------------------------------------
__global__ __launch_bounds__(256) void prep_w6(
    const float* __restrict__ w0, const float* __restrict__ s0,
    const float* __restrict__ w1, const float* __restrict__ s1,
    const float* __restrict__ w2, const float* __restrict__ s2,
    const float* __restrict__ w3, const float* __restrict__ s3,
    const float* __restrict__ w4, const float* __restrict__ s4,
    const float* __restrict__ w5, const float* __restrict__ s5,
    unsigned short* __restrict__ W2base) {
  const int set = blockIdx.y;
  const float* wl[6] = {w0, w1, w2, w3, w4, w5};
  const float* sl[6] = {s0, s1, s2, s3, s4, s5};
  const int cout = blockIdx.x;
  const int t = threadIdx.x;
  const float sc = sl[set][cout];
  const float* src = wl[set] + ((size_t)cout * 256 + t) * 9;
  float v[9];
#pragma unroll
  for (int k = 0; k < 9; ++k) v[k] = src[k] * sc;
  unsigned short* dst =
      W2base + (size_t)set * 256 * 2304 + (size_t)cout * 2304;
#pragma unroll
  for (int k = 0; k < 9; ++k) dst[k * 256 + t] = f2bf(v[k]);
}

// ---------------------------------------------------------------------------
// zero_borders: zero only the pad borders of the 5 padded NHWC buffers.
// ---------------------------------------------------------------------------
__global__ __launch_bounds__(256) void zero_borders(
    unsigned short* __restrict__ XP, unsigned short* __restrict__ QP,
    unsigned short* __restrict__ KP, unsigned short* __restrict__ VP,
    unsigned short* __restrict__ AP) {
  const int buf = blockIdx.y >> 2, b = blockIdx.y & 3;
  const int P = (buf == 4) ? 68 : 66;
  const int pad = (buf == 4) ? 2 : 1;
  const int nb = P * P - 64 * 64;
  const int i = blockIdx.x * 256 + threadIdx.x;
  const int pxi = i >> 5, ch = (i & 31) * 8;
  if (pxi >= nb) return;
  const int topbot = 2 * pad * P;
  int h, w;
  if (pxi < topbot) {
    const int r = pxi / P, c = pxi - r * P;
    h = (r < pad) ? r : P - 2 * pad + r;
    w = c;
  } else {
    const int j = pxi - topbot;
    const int r = j / (2 * pad), c = j - r * 2 * pad;
    h = pad + r;
    w = (c < pad) ? c : P - 2 * pad + c;
  }
  unsigned short* base = buf == 0 ? XP : buf == 1 ? QP : buf == 2 ? KP
                         : buf == 3 ? VP : AP;
  const u16x8 z = {0, 0, 0, 0, 0, 0, 0, 0};
  *(u16x8*)&base[((size_t)(b * P + h) * P + w) * 256 + ch] = z;
}

// ---------------------------------------------------------------------------
// pad_cast: NCHW fp32 -> NHWC bf16 padded-1, via LDS transpose (coalesced).
// ---------------------------------------------------------------------------
__global__ __launch_bounds__(256) void pad_cast(const float* __restrict__ x,
                                                unsigned short* __restrict__ Xp) {
  __shared__ float sm[64][65];
  const int bid = blockIdx.x;
  const int ct = bid & 3;
  const int h = (bid >> 2) & 63;
  const int b = bid >> 8;
  const int t = threadIdx.x;
  const int wl = t & 63, cr = t >> 6;
#pragma unroll
  for (int cc = 0; cc < 16; ++cc) {
    const int c = cc * 4 + cr;
    sm[c][wl] = x[((size_t)(b * 256 + ct * 64 + c) * 64 + h) * 64 + wl];
  }
  __syncthreads();
  const int ww = t >> 2, c16 = (t & 3) * 16;
  u16x8 o0, o1;
#pragma unroll
  for (int i = 0; i < 8; ++i) o0[i] = f2bf(sm[c16 + i][ww]);
#pragma unroll
  for (int i = 0; i < 8; ++i) o1[i] = f2bf(sm[c16 + 8 + i][ww]);
  const size_t base =
      ((size_t)(b * 66 + h + 1) * 66 + (ww + 1)) * 256 + ct * 64 + c16;
  *(u16x8*)&Xp[base] = o0;
  *(u16x8*)&Xp[base + 8] = o1;
}

// ---------------------------------------------------------------------------
// conv_qkv<D>: 3x3 dilated conv (C=256->256) x3 weight sets, BN+LeakyReLU.
// 8-phase-style schedule (T3+T4+T5): per K-step (64 cin) 4 phases of
// {ds_read subtile || issue gload_lds -> s_barrier -> lgkmcnt(0) ->
//  sched_barrier -> setprio(1) MFMA cluster setprio(0) -> s_barrier},
// counted vmcnt(2) once per step (2 next-step loads issued before the wait).
// Block: 64 cout x 256 px (4 rows) x 3 convs, 512 thr, LDS 112KB dbuf.
// ---------------------------------------------------------------------------
template <int D>
__global__ __launch_bounds__(512, 2) void conv_qkv(
    const unsigned short* __restrict__ Xp, const unsigned short* __restrict__ Wq,
    const unsigned short* __restrict__ Wk, const unsigned short* __restrict__ Wv,
    const float* __restrict__ bq, const float* __restrict__ bk,
    const float* __restrict__ bv, unsigned short* __restrict__ Qo,
    unsigned short* __restrict__ Ko, unsigned short* __restrict__ Vo) {
  constexpr int P = 64 + 2 * D;
  constexpr int HALF = 256 * 64 + 3 * 64 * 64;  // 28672 u16 = 56KB
  __shared__ __align__(16) unsigned short lds[2 * HALF];  // 112KB

  const int tid = threadIdx.x;
  const int lane = tid & 63;
  const int wid = tid >> 6;
  const int wm = wid >> 2;  // 0..1
  const int wn = wid & 3;   // 0..3
  const int m0 = blockIdx.x * 64;
  const int rg = blockIdx.y;
  const int b = rg >> 4;
  const int h0 = (rg & 15) * 4;

  f32x4 acc[3][2][4];
#pragma unroll
  for (int c = 0; c < 3; ++c)
#pragma unroll
    for (int m = 0; m < 2; ++m)
#pragma unroll
      for (int n = 0; n < 4; ++n) acc[c][m][n] = (f32x4){0.f, 0.f, 0.f, 0.f};

  // staging addressing: source pre-swizzled (rule #21), LDS linear
  const int col = tid >> 3;                 // 0..63
  const int j3 = (tid & 7) ^ (col & 7);     // swizzled cin-chunk
  const unsigned short* wptr[3] = {Wq, Wk, Wv};
  const size_t aBase = (size_t)(m0 + col) * 2304 + j3 * 8;
  const size_t bBase0 = ((size_t)(b * P + h0) * P + col) * 256 + j3 * 8;
  const int ldsOff = tid * 8;

  // stage chunks [c0,c1) of step s into half hf. chunks 0..3 = B rows, 4..6 = A convs
  auto GL = [&](int s, int c0, int c1, int hf) {
    const int t = s >> 2, kb = s & 3;
    const int ty = t / 3, tx = t - ty * 3;
    const size_t tapOff = ((size_t)(ty * D) * P + tx * D) * 256 + kb * 64;
    const int kOff = t * 256 + kb * 64;
    unsigned short* base = &lds[hf * HALF];
#pragma unroll
    for (int c = c0; c < c1; ++c) {
      if (c < 4)
        gload16(Xp + bBase0 + (size_t)c * P * 256 + tapOff,
                &base[ldsOff + c * 4096]);
      else
        gload16(wptr[c - 4] + aBase + kOff,
                &base[16384 + (c - 4) * 4096 + ldsOff]);
    }
  };

  auto RD_B = [&](short8* bfr, int kk, const unsigned short* base) {
    const int jc = kk * 4 + (lane >> 4);
#pragma unroll
    for (int n = 0; n < 4; ++n) {
      const int row = wn * 64 + n * 16 + (lane & 15);
      bfr[n] = *(const short8*)&base[row * 64 + ((jc ^ (row & 7)) << 3)];
    }
  };
  auto RD_A = [&](short8* afr, int c, int kk, const unsigned short* base) {
    const int jc = kk * 4 + (lane >> 4);
#pragma unroll
    for (int m = 0; m < 2; ++m) {
      const int row = wm * 32 + m * 16 + (lane & 15);
      afr[m] = *(const short8*)&base[16384 + c * 4096 + row * 64 +
                                     ((jc ^ (row & 7)) << 3)];
    }
  };
  auto MFMA8 = [&](int c, const short8* afr, const short8* bfr) {
#pragma unroll
    for (int m = 0; m < 2; ++m)
#pragma unroll
      for (int n = 0; n < 4; ++n)
        acc[c][m][n] = __builtin_amdgcn_mfma_f32_16x16x32_bf16(
            afr[m], bfr[n], acc[c][m][n], 0, 0, 0);
  };

#define LGKM0_FENCE                                   \
  asm volatile("s_waitcnt lgkmcnt(0)" ::: "memory"); \
  __builtin_amdgcn_sched_barrier(0)

  GL(0, 0, 7, 0);  // prologue: full stage of step 0
#pragma unroll 1
  for (int s = 0; s < 36; ++s) {
    const int p = s & 1;
    const unsigned short* base = &lds[p * HALF];
    const bool last = (s == 35);
    if (!last) {
      GL(s + 1, 0, 2, p ^ 1);
      asm volatile("s_waitcnt vmcnt(2)" ::: "memory");
    } else {
      asm volatile("s_waitcnt vmcnt(0)" ::: "memory");
    }
    __builtin_amdgcn_sched_barrier(0);
    __builtin_amdgcn_s_barrier();  // buf p fully staged for all waves

    short8 bfr[4], a0[2], a1[2], a2[2];
    // ---- phase 0A: kk=0, conv 0
    RD_B(bfr, 0, base);
    RD_A(a0, 0, 0, base);
    if (!last) GL(s + 1, 2, 4, p ^ 1);
    __builtin_amdgcn_s_barrier();
    LGKM0_FENCE;
    __builtin_amdgcn_s_setprio(1);
    MFMA8(0, a0, bfr);
    __builtin_amdgcn_s_setprio(0);
    __builtin_amdgcn_s_barrier();
    // ---- phase 0B: kk=0, convs 1,2
    RD_A(a1, 1, 0, base);
    RD_A(a2, 2, 0, base);
    if (!last) GL(s + 1, 4, 6, p ^ 1);
    __builtin_amdgcn_s_barrier();
    LGKM0_FENCE;
    __builtin_amdgcn_s_setprio(1);
    MFMA8(1, a1, bfr);
    MFMA8(2, a2, bfr);
    __builtin_amdgcn_s_setprio(0);
    __builtin_amdgcn_s_barrier();
    // ---- phase 1A: kk=1, conv 0
    RD_B(bfr, 1, base);
    RD_A(a0, 0, 1, base);
    if (!last) GL(s + 1, 6, 7, p ^ 1);
    __builtin_amdgcn_s_barrier();
    LGKM0_FENCE;
    __builtin_amdgcn_s_setprio(1);
    MFMA8(0, a0, bfr);
    __builtin_amdgcn_s_setprio(0);
    __builtin_amdgcn_s_barrier();
    // ---- phase 1B: kk=1, convs 1,2
    RD_A(a1, 1, 1, base);
    RD_A(a2, 2, 1, base);
    __builtin_amdgcn_s_barrier();
    LGKM0_FENCE;
    __builtin_amdgcn_s_setprio(1);
    MFMA8(1, a1, bfr);
    MFMA8(2, a2, bfr);
    __builtin_amdgcn_s_setprio(0);
    __builtin_amdgcn_s_barrier();  // buf p safe to overwrite next step
  }
#undef LGKM0_FENCE

  // epilogue: + bias, LeakyReLU(0.1), write NHWC bf16 padded-1 (66x66)
  const float* bias[3] = {bq, bk, bv};
  unsigned short* outp[3] = {Qo, Ko, Vo};
  const int r4 = (lane >> 4) << 2;
#pragma unroll
  for (int c = 0; c < 3; ++c) {
#pragma unroll
    for (int m = 0; m < 2; ++m) {
      const int cout = m0 + wm * 32 + m * 16 + r4;
      const f32x4 bb = *(const f32x4*)&bias[c][cout];
#pragma unroll
      for (int n = 0; n < 4; ++n) {
        const int px = wn * 64 + n * 16 + (lane & 15);  // 0..255
        const int ww = px & 63;
        const int hh = h0 + (px >> 6);
        const size_t off =
            ((size_t)(b * 66 + hh + 1) * 66 + (ww + 1)) * 256 + cout;
        u16x4 pk;
#pragma unroll
        for (int r = 0; r < 4; ++r) {
          float f = acc[c][m][n][r] + bb[r];
          f = f > 0.f ? f : 0.1f * f;
          pk[r] = f2bf(f);
        }
        *(u16x4*)&outp[c][off] = pk;
      }
    }
  }
}

// ---------------------------------------------------------------------------
// attn3x3<MODE>: per-channel softmax over 3x3 neighborhood (XCD-swizzled).
// ---------------------------------------------------------------------------
template <int MODE>
__global__ __launch_bounds__(256) void attn3x3(
    const unsigned short* __restrict__ Qp, const unsigned short* __restrict__ Kp,
    const unsigned short* __restrict__ Vp, unsigned short* __restrict__ outB,
    float* __restrict__ outF) {
  __shared__ float so[8][257];
  const int tid = threadIdx.x;
  const int bid = ((blockIdx.x & 7) << 8) + (blockIdx.x >> 3);  // bijective
  const int gid = bid * 256 + tid;
  const int cch = gid & 31;
  const int pix = gid >> 5;
  const int b = pix >> 12, h = (pix >> 6) & 63, w = pix & 63;
  const int c0 = cch * 8;

  const size_t cen = ((size_t)(b * 66 + h + 1) * 66 + (w + 1)) * 256 + c0;
  const size_t tl = ((size_t)(b * 66 + h) * 66 + w) * 256 + c0;

  float q[8];
  {
    u16x8 u = *(const u16x8*)&Qp[cen];
#pragma unroll
    for (int i = 0; i < 8; ++i) q[i] = bf2f(u[i]) * 0.0625f;  // 1/sqrt(256)
  }
  float s[9][8];
#pragma unroll
  for (int t = 0; t < 9; ++t) {
    u16x8 u = *(const u16x8*)&Kp[tl + (size_t)((t / 3) * 66 + (t % 3)) * 256];
#pragma unroll
    for (int i = 0; i < 8; ++i) s[t][i] = q[i] * bf2f(u[i]);
  }
  float mx[8];
#pragma unroll
  for (int i = 0; i < 8; ++i) {
    float m = s[0][i];
#pragma unroll
    for (int t = 1; t < 9; ++t) m = fmaxf(m, s[t][i]);
    mx[i] = m;
  }
  float num[8], den[8];
#pragma unroll
  for (int i = 0; i < 8; ++i) { num[i] = 0.f; den[i] = 0.f; }
#pragma unroll
  for (int t = 0; t < 9; ++t) {
    u16x8 u = *(const u16x8*)&Vp[tl + (size_t)((t / 3) * 66 + (t % 3)) * 256];
#pragma unroll
    for (int i = 0; i < 8; ++i) {
      const float e = __expf(s[t][i] - mx[i]);
      den[i] += e;
      num[i] += e * bf2f(u[i]);
    }
  }

  if (MODE == 0) {
    u16x8 o;
#pragma unroll
    for (int i = 0; i < 8; ++i) o[i] = f2bf(num[i] / den[i]);
    *(u16x8*)&outB[((size_t)(b * 68 + h + 2) * 68 + (w + 2)) * 256 + c0] = o;
  } else {
    const int ps = tid >> 5;
#pragma unroll
    for (int i = 0; i < 8; ++i) so[ps][c0 + i] = num[i] / den[i];
    __syncthreads();
    const int pix0 = bid * 8;
    const int b2 = pix0 >> 12, h2 = (pix0 >> 6) & 63, w0 = pix0 & 63;
    const int c = tid;
    const size_t ob = (((size_t)b2 * 256 + c) * 64 + h2) * 64 + w0;
    f32x4 v0 = (f32x4){so[0][c], so[1][c], so[2][c], so[3][c]};
    f32x4 v1 = (f32x4){so[4][c], so[5][c], so[6][c], so[7][c]};
    *(f32x4*)&outF[ob] = v0;
    *(f32x4*)&outF[ob + 4] = v1;
  }
}

// ---------------------------------------------------------------------------
extern "C" void kernel_launch(void* const* d_in, const int* in_sizes, int n_in,
                              void* d_out, int out_size, void* d_ws,
                              size_t ws_size, hipStream_t stream) {
  (void)in_sizes; (void)n_in; (void)out_size; (void)ws_size;
  const float* x = (const float*)d_in[0];
  const float* wqs[6] = {(const float*)d_in[1],  (const float*)d_in[4],
                         (const float*)d_in[7],  (const float*)d_in[10],
                         (const float*)d_in[13], (const float*)d_in[16]};
  const float* scs[6] = {(const float*)d_in[2],  (const float*)d_in[5],
                         (const float*)d_in[8],  (const float*)d_in[11],
                         (const float*)d_in[14], (const float*)d_in[17]};
  const float* bq1 = (const float*)d_in[3];
  const float* bk1 = (const float*)d_in[6];
  const float* bv1 = (const float*)d_in[9];
  const float* bq2 = (const float*)d_in[12];
  const float* bk2 = (const float*)d_in[15];
  const float* bv2 = (const float*)d_in[18];

  char* ws = (char*)d_ws;
  const size_t SZ66 = (size_t)4 * 66 * 66 * 256 * 2;
  const size_t SZ68 = (size_t)4 * 68 * 68 * 256 * 2;
  unsigned short* XP = (unsigned short*)(ws);
  unsigned short* QP = (unsigned short*)(ws + SZ66);
  unsigned short* KP = (unsigned short*)(ws + 2 * SZ66);
  unsigned short* VP = (unsigned short*)(ws + 3 * SZ66);
  unsigned short* AP = (unsigned short*)(ws + 4 * SZ66);
  const size_t wbase = 4 * SZ66 + SZ68;
  unsigned short* W2base = (unsigned short*)(ws + wbase);
  const size_t WSET = (size_t)256 * 2304;

  zero_borders<<<dim3(66, 20), 256, 0, stream>>>(XP, QP, KP, VP, AP);
  prep_w6<<<dim3(256, 6), 256, 0, stream>>>(
      wqs[0], scs[0], wqs[1], scs[1], wqs[2], scs[2], wqs[3], scs[3], wqs[4],
      scs[4], wqs[5], scs[5], W2base);
  pad_cast<<<1024, 256, 0, stream>>>(x, XP);

  conv_qkv<1><<<dim3(4, 64), 512, 0, stream>>>(
      XP, W2base, W2base + WSET, W2base + 2 * WSET, bq1, bk1, bv1, QP, KP, VP);
  attn3x3<0><<<2048, 256, 0, stream>>>(QP, KP, VP, AP, nullptr);
  conv_qkv<2><<<dim3(4, 64), 512, 0, stream>>>(
      AP, W2base + 3 * WSET, W2base + 4 * WSET, W2base + 5 * WSET, bq2, bk2,
      bv2, QP, KP, VP);
  attn3x3<1><<<2048, 256, 0, stream>>>(QP, KP, VP, nullptr, (float*)d_out);
}

// Round 9
// 152.394 us; speedup vs baseline: 1.1067x; 1.1067x over previous
//
#include <hip/hip_runtime.h>
#include <stdint.h>

typedef __attribute__((ext_vector_type(8))) short short8;
typedef __attribute__((ext_vector_type(4))) float f32x4;
typedef __attribute__((ext_vector_type(4))) unsigned short u16x4;
typedef __attribute__((ext_vector_type(8))) unsigned short u16x8;

#define DEV static __device__ __forceinline__

DEV unsigned short f2bf(float f) {
  unsigned u = __float_as_uint(f);
  u += 0x7FFFu + ((u >> 16) & 1u);
  return (unsigned short)(u >> 16);
}
DEV float bf2f(unsigned short s) { return __uint_as_float(((unsigned)s) << 16); }

// global -> LDS direct load, 16B per lane
DEV void gload16(const void* g, void* l) {
  __attribute__((address_space(1))) unsigned* gp =
      reinterpret_cast<__attribute__((address_space(1))) unsigned*>(
          reinterpret_cast<uintptr_t>(g));
  __attribute__((address_space(3))) unsigned* lp =
      reinterpret_cast<__attribute__((address_space(3))) unsigned*>(
          reinterpret_cast<uintptr_t>(l));
  __builtin_amdgcn_global_load_lds(gp, lp, 16, 0, 0);
}

// ---------------------------------------------------------------------------
// prologue: one launch, range-dispatched 1D grid of 3880 blocks.
//   [0,1320):        zero borders of the 5 padded NHWC buffers
//   [1320,2856):     prep weights (6 sets): W2[set][cout][tap][cin] bf16
//   [2856,3880):     pad_cast x NCHW fp32 -> XP NHWC bf16 (via LDS transpose)
// ---------------------------------------------------------------------------
__global__ __launch_bounds__(256) void prologue(
    const float* __restrict__ x,
    const float* __restrict__ w0, const float* __restrict__ s0,
    const float* __restrict__ w1, const float* __restrict__ s1,
    const float* __restrict__ w2, const float* __restrict__ s2,
    const float* __restrict__ w3, const float* __restrict__ s3,
    const float* __restrict__ w4, const float* __restrict__ s4,
    const float* __restrict__ w5, const float* __restrict__ s5,
    unsigned short* __restrict__ XP, unsigned short* __restrict__ QP,
    unsigned short* __restrict__ KP, unsigned short* __restrict__ VP,
    unsigned short* __restrict__ AP, unsigned short* __restrict__ W2base) {
  __shared__ float sm[64][65];
  const int blk = blockIdx.x;
  const int t = threadIdx.x;

  if (blk < 1320) {
    // ---- zero_borders: idx = by*66+bx of original dim3(66,20)
    const int bx = blk % 66, by = blk / 66;
    const int buf = by >> 2, b = by & 3;
    const int P = (buf == 4) ? 68 : 66;
    const int pad = (buf == 4) ? 2 : 1;
    const int nb = P * P - 64 * 64;
    const int i = bx * 256 + t;
    const int pxi = i >> 5, ch = (i & 31) * 8;
    if (pxi >= nb) return;
    const int topbot = 2 * pad * P;
    int h, w;
    if (pxi < topbot) {
      const int r = pxi / P, c = pxi - r * P;
      h = (r < pad) ? r : P - 2 * pad + r;
      w = c;
    } else {
      const int j = pxi - topbot;
      const int r = j / (2 * pad), c = j - r * 2 * pad;
      h = pad + r;
      w = (c < pad) ? c : P - 2 * pad + c;
    }
    unsigned short* base = buf == 0 ? XP : buf == 1 ? QP : buf == 2 ? KP
                           : buf == 3 ? VP : AP;
    const u16x8 z = {0, 0, 0, 0, 0, 0, 0, 0};
    *(u16x8*)&base[((size_t)(b * P + h) * P + w) * 256 + ch] = z;
  } else if (blk < 2856) {
    // ---- prep_w6: idx -> (set, cout)
    const int idx = blk - 1320;
    const int set = idx >> 8, cout = idx & 255;
    const float* wl[6] = {w0, w1, w2, w3, w4, w5};
    const float* sl[6] = {s0, s1, s2, s3, s4, s5};
    const float sc = sl[set][cout];
    const float* src = wl[set] + ((size_t)cout * 256 + t) * 9;
    float v[9];
#pragma unroll
    for (int k = 0; k < 9; ++k) v[k] = src[k] * sc;
    unsigned short* dst =
        W2base + (size_t)set * 256 * 2304 + (size_t)cout * 2304;
#pragma unroll
    for (int k = 0; k < 9; ++k) dst[k * 256 + t] = f2bf(v[k]);
  } else {
    // ---- pad_cast
    const int bid = blk - 2856;
    const int ct = bid & 3;
    const int h = (bid >> 2) & 63;
    const int b = bid >> 8;
    const int wl2 = t & 63, cr = t >> 6;
#pragma unroll
    for (int cc = 0; cc < 16; ++cc) {
      const int c = cc * 4 + cr;
      sm[c][wl2] = x[((size_t)(b * 256 + ct * 64 + c) * 64 + h) * 64 + wl2];
    }
    __syncthreads();
    const int ww = t >> 2, c16 = (t & 3) * 16;
    u16x8 o0, o1;
#pragma unroll
    for (int i = 0; i < 8; ++i) o0[i] = f2bf(sm[c16 + i][ww]);
#pragma unroll
    for (int i = 0; i < 8; ++i) o1[i] = f2bf(sm[c16 + 8 + i][ww]);
    const size_t base =
        ((size_t)(b * 66 + h + 1) * 66 + (ww + 1)) * 256 + ct * 64 + c16;
    *(u16x8*)&XP[base] = o0;
    *(u16x8*)&XP[base + 8] = o1;
  }
}

// ---------------------------------------------------------------------------
// conv_qkv<D>: 3x3 dilated conv (C=256->256) x3 weight sets, BN+LeakyReLU.
// Round-7 proven structure: 98% of measured LDS-BW ceiling (112 B/cyc/CU).
// 1D grid 512, XCD-swizzled (m0 pinned per XCD -> 884KB weight slab L2-res).
// Block: 64 cout x 128 px x 3 convs, 4 waves, LDS 80KB -> 2 blocks/CU.
// T4 counted vmcnt(10); T5 setprio around MFMA cluster.
// ---------------------------------------------------------------------------
template <int D>
__global__ __launch_bounds__(256, 2) void conv_qkv(
    const unsigned short* __restrict__ Xp, const unsigned short* __restrict__ Wq,
    const unsigned short* __restrict__ Wk, const unsigned short* __restrict__ Wv,
    const float* __restrict__ bq, const float* __restrict__ bk,
    const float* __restrict__ bv, unsigned short* __restrict__ Qo,
    unsigned short* __restrict__ Ko, unsigned short* __restrict__ Vo) {
  constexpr int P = 64 + 2 * D;
  constexpr int HALF = 128 * 64 + 3 * 64 * 64;  // 20480 ushorts = 40KB
  __shared__ __align__(16) unsigned short lds[2 * HALF];

  const int tid = threadIdx.x;
  const int lane = tid & 63;
  const int wid = tid >> 6;
  const int wm = wid >> 1;
  const int wn = wid & 1;
  const int wgid = blockIdx.x;
  const int xcd = wgid & 7;
  const int m0 = (xcd & 3) * 64;
  const int rg = (wgid >> 3) + 64 * (xcd >> 2);
  const int b = rg >> 5;
  const int h0 = (rg & 31) * 2;

  f32x4 acc[3][2][4];
#pragma unroll
  for (int c = 0; c < 3; ++c)
#pragma unroll
    for (int m = 0; m < 2; ++m)
#pragma unroll
      for (int n = 0; n < 4; ++n) acc[c][m][n] = (f32x4){0.f, 0.f, 0.f, 0.f};

  const int w0i = tid >> 3;
  const int j3 = (tid & 7) ^ (w0i & 7);
  const unsigned short* wptr[3] = {Wq, Wk, Wv};
  size_t bRow[2];
#pragma unroll
  for (int r = 0; r < 2; ++r)
    bRow[r] = ((size_t)(b * P + h0 + r) * P + w0i) * 256 + j3 * 8;
  const size_t aBase = (size_t)(m0 + w0i) * 2304 + j3 * 8;

  auto STAGE = [&](int s, int hf) {
    const int t = s >> 2, kb = s & 3;
    const int ty = t / 3, tx = t - ty * 3;
    const size_t tapOff = ((size_t)(ty * D) * P + tx * D) * 256 + kb * 64;
    const int kOff = t * 256 + kb * 64;
    unsigned short* base = &lds[hf * HALF];
#pragma unroll
    for (int k = 0; k < 4; ++k)
      gload16(Xp + bRow[k >> 1] + (size_t)(32 * (k & 1)) * 256 + tapOff,
              &base[(k * 256 + tid) * 8]);
#pragma unroll
    for (int k = 0; k < 6; ++k)
      gload16(wptr[k >> 1] + aBase + (size_t)(k & 1) * 32 * 2304 + kOff,
              &base[8192 + (k * 256 + tid) * 8]);
  };

  auto COMPUTE = [&](int hf) {
    const unsigned short* base = &lds[hf * HALF];
#pragma unroll
    for (int kk = 0; kk < 2; ++kk) {
      const int jc = kk * 4 + (lane >> 4);
      short8 bfr[4], afr[3][2];
#pragma unroll
      for (int n = 0; n < 4; ++n) {
        const int row = wn * 64 + n * 16 + (lane & 15);
        bfr[n] = *(const short8*)&base[row * 64 + ((jc ^ (row & 7)) << 3)];
      }
#pragma unroll
      for (int c = 0; c < 3; ++c)
#pragma unroll
        for (int m = 0; m < 2; ++m) {
          const int row = wm * 32 + m * 16 + (lane & 15);
          afr[c][m] = *(const short8*)&base[8192 + c * 4096 + row * 64 +
                                            ((jc ^ (row & 7)) << 3)];
        }
      __builtin_amdgcn_s_setprio(1);
#pragma unroll
      for (int c = 0; c < 3; ++c)
#pragma unroll
        for (int m = 0; m < 2; ++m)
#pragma unroll
          for (int n = 0; n < 4; ++n)
            acc[c][m][n] = __builtin_amdgcn_mfma_f32_16x16x32_bf16(
                afr[c][m], bfr[n], acc[c][m][n], 0, 0, 0);
      __builtin_amdgcn_s_setprio(0);
    }
  };

  STAGE(0, 0);
#pragma unroll 1
  for (int s = 0; s < 35; ++s) {
    const int p = s & 1;
    STAGE(s + 1, p ^ 1);
    asm volatile("s_waitcnt vmcnt(10)" ::: "memory");
    __builtin_amdgcn_s_barrier();
    COMPUTE(p);
    __builtin_amdgcn_s_barrier();
  }
  asm volatile("s_waitcnt vmcnt(0)" ::: "memory");
  __builtin_amdgcn_s_barrier();
  COMPUTE(1);

  const float* bias[3] = {bq, bk, bv};
  unsigned short* outp[3] = {Qo, Ko, Vo};
  const int r4 = (lane >> 4) << 2;
#pragma unroll
  for (int c = 0; c < 3; ++c) {
#pragma unroll
    for (int m = 0; m < 2; ++m) {
      const int cout = m0 + wm * 32 + m * 16 + r4;
      const f32x4 bb = *(const f32x4*)&bias[c][cout];
#pragma unroll
      for (int n = 0; n < 4; ++n) {
        const int px = wn * 64 + n * 16 + (lane & 15);
        const int ww = px & 63;
        const int hh = h0 + (px >> 6);
        const size_t off =
            ((size_t)(b * 66 + hh + 1) * 66 + (ww + 1)) * 256 + cout;
        u16x4 pk;
#pragma unroll
        for (int r = 0; r < 4; ++r) {
          float f = acc[c][m][n][r] + bb[r];
          f = f > 0.f ? f : 0.1f * f;
          pk[r] = f2bf(f);
        }
        *(u16x4*)&outp[c][off] = pk;
      }
    }
  }
}

// ---------------------------------------------------------------------------
// attn3x3<MODE>: per-channel softmax over 3x3 neighborhood (XCD-swizzled).
// rcp instead of divide in the normalize.
// ---------------------------------------------------------------------------
template <int MODE>
__global__ __launch_bounds__(256) void attn3x3(
    const unsigned short* __restrict__ Qp, const unsigned short* __restrict__ Kp,
    const unsigned short* __restrict__ Vp, unsigned short* __restrict__ outB,
    float* __restrict__ outF) {
  __shared__ float so[8][257];
  const int tid = threadIdx.x;
  const int bid = ((blockIdx.x & 7) << 8) + (blockIdx.x >> 3);  // bijective
  const int gid = bid * 256 + tid;
  const int cch = gid & 31;
  const int pix = gid >> 5;
  const int b = pix >> 12, h = (pix >> 6) & 63, w = pix & 63;
  const int c0 = cch * 8;

  const size_t cen = ((size_t)(b * 66 + h + 1) * 66 + (w + 1)) * 256 + c0;
  const size_t tl = ((size_t)(b * 66 + h) * 66 + w) * 256 + c0;

  float q[8];
  {
    u16x8 u = *(const u16x8*)&Qp[cen];
#pragma unroll
    for (int i = 0; i < 8; ++i) q[i] = bf2f(u[i]) * 0.0625f;  // 1/sqrt(256)
  }
  float s[9][8];
#pragma unroll
  for (int t = 0; t < 9; ++t) {
    u16x8 u = *(const u16x8*)&Kp[tl + (size_t)((t / 3) * 66 + (t % 3)) * 256];
#pragma unroll
    for (int i = 0; i < 8; ++i) s[t][i] = q[i] * bf2f(u[i]);
  }
  float mx[8];
#pragma unroll
  for (int i = 0; i < 8; ++i) {
    float m = s[0][i];
#pragma unroll
    for (int t = 1; t < 9; ++t) m = fmaxf(m, s[t][i]);
    mx[i] = m;
  }
  float num[8], den[8];
#pragma unroll
  for (int i = 0; i < 8; ++i) { num[i] = 0.f; den[i] = 0.f; }
#pragma unroll
  for (int t = 0; t < 9; ++t) {
    u16x8 u = *(const u16x8*)&Vp[tl + (size_t)((t / 3) * 66 + (t % 3)) * 256];
#pragma unroll
    for (int i = 0; i < 8; ++i) {
      const float e = __expf(s[t][i] - mx[i]);
      den[i] += e;
      num[i] += e * bf2f(u[i]);
    }
  }

  if (MODE == 0) {
    u16x8 o;
#pragma unroll
    for (int i = 0; i < 8; ++i)
      o[i] = f2bf(num[i] * __builtin_amdgcn_rcpf(den[i]));
    *(u16x8*)&outB[((size_t)(b * 68 + h + 2) * 68 + (w + 2)) * 256 + c0] = o;
  } else {
    const int ps = tid >> 5;
#pragma unroll
    for (int i = 0; i < 8; ++i)
      so[ps][c0 + i] = num[i] * __builtin_amdgcn_rcpf(den[i]);
    __syncthreads();
    const int pix0 = bid * 8;
    const int b2 = pix0 >> 12, h2 = (pix0 >> 6) & 63, w0 = pix0 & 63;
    const int c = tid;
    const size_t ob = (((size_t)b2 * 256 + c) * 64 + h2) * 64 + w0;
    f32x4 v0 = (f32x4){so[0][c], so[1][c], so[2][c], so[3][c]};
    f32x4 v1 = (f32x4){so[4][c], so[5][c], so[6][c], so[7][c]};
    *(f32x4*)&outF[ob] = v0;
    *(f32x4*)&outF[ob + 4] = v1;
  }
}

// ---------------------------------------------------------------------------
extern "C" void kernel_launch(void* const* d_in, const int* in_sizes, int n_in,
                              void* d_out, int out_size, void* d_ws,
                              size_t ws_size, hipStream_t stream) {
  (void)in_sizes; (void)n_in; (void)out_size; (void)ws_size;
  const float* x = (const float*)d_in[0];
  const float* wqs[6] = {(const float*)d_in[1],  (const float*)d_in[4],
                         (const float*)d_in[7],  (const float*)d_in[10],
                         (const float*)d_in[13], (const float*)d_in[16]};
  const float* scs[6] = {(const float*)d_in[2],  (const float*)d_in[5],
                         (const float*)d_in[8],  (const float*)d_in[11],
                         (const float*)d_in[14], (const float*)d_in[17]};
  const float* bq1 = (const float*)d_in[3];
  const float* bk1 = (const float*)d_in[6];
  const float* bv1 = (const float*)d_in[9];
  const float* bq2 = (const float*)d_in[12];
  const float* bk2 = (const float*)d_in[15];
  const float* bv2 = (const float*)d_in[18];

  char* ws = (char*)d_ws;
  const size_t SZ66 = (size_t)4 * 66 * 66 * 256 * 2;
  const size_t SZ68 = (size_t)4 * 68 * 68 * 256 * 2;
  unsigned short* XP = (unsigned short*)(ws);
  unsigned short* QP = (unsigned short*)(ws + SZ66);
  unsigned short* KP = (unsigned short*)(ws + 2 * SZ66);
  unsigned short* VP = (unsigned short*)(ws + 3 * SZ66);
  unsigned short* AP = (unsigned short*)(ws + 4 * SZ66);
  const size_t wbase = 4 * SZ66 + SZ68;
  unsigned short* W2base = (unsigned short*)(ws + wbase);
  const size_t WSET = (size_t)256 * 2304;

  prologue<<<3880, 256, 0, stream>>>(
      x, wqs[0], scs[0], wqs[1], scs[1], wqs[2], scs[2], wqs[3], scs[3],
      wqs[4], scs[4], wqs[5], scs[5], XP, QP, KP, VP, AP, W2base);

  conv_qkv<1><<<512, 256, 0, stream>>>(
      XP, W2base, W2base + WSET, W2base + 2 * WSET, bq1, bk1, bv1, QP, KP, VP);
  attn3x3<0><<<2048, 256, 0, stream>>>(QP, KP, VP, AP, nullptr);
  conv_qkv<2><<<512, 256, 0, stream>>>(
      AP, W2base + 3 * WSET, W2base + 4 * WSET, W2base + 5 * WSET, bq2, bk2,
      bv2, QP, KP, VP);
  attn3x3<1><<<2048, 256, 0, stream>>>(QP, KP, VP, nullptr, (float*)d_out);
}